// Round 7
// baseline (270.543 us; speedup 1.0000x reference)
//
#include <hip/hip_runtime.h>

typedef unsigned short u16;
typedef unsigned int u32;
typedef __attribute__((ext_vector_type(8))) short short8;
typedef __attribute__((ext_vector_type(8))) _Float16 half8;
typedef __attribute__((ext_vector_type(4))) float floatx4;
typedef __attribute__((ext_vector_type(4))) unsigned short ushortx4;
typedef __attribute__((ext_vector_type(4))) unsigned int uint4v;

#define DEV static __device__ __forceinline__

DEV float bf2f(u16 u) { union { unsigned u; float f; } v; v.u = ((unsigned)u) << 16; return v.f; }
DEV u16 f2bf(float f) {
  union { float f; unsigned u; } v; v.f = f;
  return (u16)((v.u + 0x7FFFu + ((v.u >> 16) & 1u)) >> 16);  // RNE; finite inputs
}
DEV u16 f2h(float f) { return __builtin_bit_cast(u16, (_Float16)f); }  // v_cvt_f16_f32 (RNE)
// pack two floats to two fp16 in one v_cvt_pkrtz_f16_f32: a -> low u16, b -> high u16
DEV u32 pkh(float a, float b) {
  return __builtin_bit_cast(u32, __builtin_amdgcn_cvt_pkrtz(a, b));
}
// pack two floats to two bf16 (round-half-up) in one v_perm: a -> low u16, b -> high u16
DEV u32 pkbf(float a, float b) {
  union { float f; u32 u; } x, y; x.f = a; y.f = b;
  return __builtin_amdgcn_perm(y.u + 0x8000u, x.u + 0x8000u, 0x07060302u);
}
DEV float fexp2(float x) { return __builtin_amdgcn_exp2f(x); }  // v_exp_f32

// async global->LDS, 16B/lane, LDS dest = wave-uniform base + lane*16 (m97-proven form)
#define GLDS(g, l) __builtin_amdgcn_global_load_lds( \
    (const __attribute__((address_space(1))) void*)(g), \
    (__attribute__((address_space(3))) void*)(l), 16, 0, 0)

// ---------------- projection GEMMs: fused fp32->bf16 staging (convert kernel deleted) ----------------
// R7: reads fp32 X/W straight from d_in; converts to bf16 while staging into LDS
// (float4 x2 -> pkbf x4 -> ds_write_b128 to the same [row][32] layout GLDS produced).
// Inner fragment/MFMA/epilogue logic identical to the proven m97-style kernel.
// Grid 768 (1D), XCD-swizzled so each XCD owns 3 (bn,z) combos: the 32 concurrent CUs
// of an XCD share one hot 256KB B-panel in their private L2 while A streams.
struct GemmArg {
  const float* x;    // fp32 [4096][1024]
  const float* w;    // fp32 [1024][1024] (torch: y = x @ W.T + b -> NT gemm)
  const float* bias; // fp32 [1024]
  u16* dst;
  int mode;          // 0=Q (BHSD, *0.125*log2e)  1=K (BHSD)  2=V^T fp16 (BHDS)
};

__global__ __launch_bounds__(256, 2) void gemm_qkv(GemmArg g0, GemmArg g1, GemmArg g2) {
  // XCD swizzle: bid -> gidx chunks of 96 per XCD; within a chunk bm varies fastest,
  // so one (bn,z) B-panel is hot across the XCD's CUs at a time.
  const int bid = blockIdx.x;
  const int gidx = (bid & 7) * 96 + (bid >> 3);   // 768 % 8 == 0: bijective
  const int bm = gidx & 31;
  const int bnz = gidx >> 5;                      // 0..23
  const int bn = bnz & 7, z = bnz >> 3;
  GemmArg g = (z == 0) ? g0 : ((z == 1) ? g1 : g2);

  __shared__ u16 As[128 * 32];
  __shared__ u16 Bs[128 * 32];
  const int tid = threadIdx.x, w = tid >> 6, l = tid & 63;
  const int l15 = l & 15, quad = l >> 4;
  const int wm = w >> 1, wn = w & 1;

  floatx4 acc[4][4];
#pragma unroll
  for (int i = 0; i < 4; ++i)
#pragma unroll
    for (int j = 0; j < 4; ++j) acc[i][j] = (floatx4){0.f, 0.f, 0.f, 0.f};

  // per-thread global sources (fp32) and LDS dests (bf16), matching the GLDS layout:
  // row = base + w*16 + (l>>2) (+p*64), col chunk = (l&3)*8
  const float* xr = g.x + (long)(bm * 128 + w * 16 + (l >> 2)) * 1024 + (l & 3) * 8;
  const float* wr = g.w + (long)(bn * 128 + w * 16 + (l >> 2)) * 1024 + (l & 3) * 8;
  u16* asd = &As[(w * 16 + (l >> 2)) * 32 + (l & 3) * 8];
  u16* bsd = &Bs[(w * 16 + (l >> 2)) * 32 + (l & 3) * 8];

  for (int kt = 0; kt < 32; ++kt) {
    const int k0 = kt * 32;
    __syncthreads();
#pragma unroll
    for (int p = 0; p < 2; ++p) {
      floatx4 a0 = *(const floatx4*)(xr + (long)p * 64 * 1024 + k0);
      floatx4 a1 = *(const floatx4*)(xr + (long)p * 64 * 1024 + k0 + 4);
      floatx4 b0 = *(const floatx4*)(wr + (long)p * 64 * 1024 + k0);
      floatx4 b1 = *(const floatx4*)(wr + (long)p * 64 * 1024 + k0 + 4);
      uint4v da = {pkbf(a0[0], a0[1]), pkbf(a0[2], a0[3]), pkbf(a1[0], a1[1]), pkbf(a1[2], a1[3])};
      uint4v db = {pkbf(b0[0], b0[1]), pkbf(b0[2], b0[3]), pkbf(b1[0], b1[1]), pkbf(b1[2], b1[3])};
      *(uint4v*)(asd + p * 64 * 32) = da;
      *(uint4v*)(bsd + p * 64 * 32) = db;
    }
    __syncthreads();
    short8 af[4], bfr[4];
#pragma unroll
    for (int mi = 0; mi < 4; ++mi)
      af[mi] = *(const short8*)&As[(wm * 64 + mi * 16 + l15) * 32 + quad * 8];
#pragma unroll
    for (int ni = 0; ni < 4; ++ni)
      bfr[ni] = *(const short8*)&Bs[(wn * 64 + ni * 16 + l15) * 32 + quad * 8];
#pragma unroll
    for (int mi = 0; mi < 4; ++mi)
#pragma unroll
      for (int ni = 0; ni < 4; ++ni)
        acc[mi][ni] = __builtin_amdgcn_mfma_f32_16x16x32_bf16(af[mi], bfr[ni], acc[mi][ni], 0, 0, 0);
  }

  float bv[4];
#pragma unroll
  for (int ni = 0; ni < 4; ++ni) bv[ni] = g.bias[bn * 128 + wn * 64 + ni * 16 + l15];

  // C/D layout: col = lane&15, row = quad*4 + reg  [m89/m91]
#pragma unroll
  for (int mi = 0; mi < 4; ++mi) {
    const int mbase = bm * 128 + wm * 64 + mi * 16 + quad * 4;
#pragma unroll
    for (int ni = 0; ni < 4; ++ni) {
      const int n = bn * 128 + wn * 64 + ni * 16 + l15;
      if (g.mode == 2) {  // V^T [B,H,64,2048] in fp16 (feeds f16 PV MFMA)
        const int b = mbase >> 11, s = mbase & 2047;
        const int h = n >> 6, d = n & 63;
        ushortx4 u;
#pragma unroll
        for (int r = 0; r < 4; ++r) u[r] = f2h(acc[mi][ni][r] + bv[ni]);
        *(ushortx4*)&g.dst[((long)(b * 16 + h) * 64 + d) * 2048 + s] = u;
      } else {  // Q/K -> [B,H,2048,64]; Q folds 1/sqrt(64) * log2(e) for exp2 softmax
        const float sc = (g.mode == 0) ? 0.18033688011f : 1.0f;
        const int h = n >> 6, d = n & 63;
#pragma unroll
        for (int r = 0; r < 4; ++r) {
          const int m = mbase + r, b = m >> 11, s = m & 2047;
          g.dst[((long)(b * 16 + h) * 2048 + s) * 64 + d] = f2bf((acc[mi][ni][r] + bv[ni]) * sc);
        }
      }
    }
  }
}

// ---------------- output GEMM: 64x128 tile, 512 blocks (was 256 = 1 block/CU) ----------------
// R7: o-proj was grid-limited to exactly 1 block/CU -> zero inter-block overlap, every
// barrier drain fully exposed. BM=64 doubles the grid (2+ blocks/CU restores the m114
// implicit-overlap mechanism). A = attn output Xb (bf16, GLDS-staged); B = Wo fp32
// (fused convert, re-read from per-XCD-resident L2 panel). Writes fp32 d_out.
__global__ __launch_bounds__(256, 2) void gemm_o(const u16* __restrict__ x,
                                                 const float* __restrict__ wo,
                                                 const float* __restrict__ bias,
                                                 float* __restrict__ dst) {
  const int bid = blockIdx.x;
  const int gidx = (bid & 7) * 64 + (bid >> 3);   // 512 % 8 == 0: bijective
  const int bm = gidx & 63;                       // bn = xcd: B-panel resident per-XCD L2
  const int bn = gidx >> 6;

  __shared__ u16 As[64 * 32];
  __shared__ u16 Bs[128 * 32];
  const int tid = threadIdx.x, w = tid >> 6, l = tid & 63;
  const int l15 = l & 15, quad = l >> 4;
  const int wm = w >> 1, wn = w & 1;   // wave tile: 32m x 64n

  floatx4 acc[2][4];
#pragma unroll
  for (int i = 0; i < 2; ++i)
#pragma unroll
    for (int j = 0; j < 4; ++j) acc[i][j] = (floatx4){0.f, 0.f, 0.f, 0.f};

  const u16* xb = x + (long)(bm * 64 + w * 16 + (l >> 2)) * 1024 + (l & 3) * 8;
  const float* wr = wo + (long)(bn * 128 + w * 16 + (l >> 2)) * 1024 + (l & 3) * 8;
  u16* asb = &As[(w * 16) * 32];
  u16* bsd = &Bs[(w * 16 + (l >> 2)) * 32 + (l & 3) * 8];

  for (int kt = 0; kt < 32; ++kt) {
    const int k0 = kt * 32;
    __syncthreads();
    GLDS(xb + k0, asb);
#pragma unroll
    for (int p = 0; p < 2; ++p) {
      floatx4 b0 = *(const floatx4*)(wr + (long)p * 64 * 1024 + k0);
      floatx4 b1 = *(const floatx4*)(wr + (long)p * 64 * 1024 + k0 + 4);
      uint4v db = {pkbf(b0[0], b0[1]), pkbf(b0[2], b0[3]), pkbf(b1[0], b1[1]), pkbf(b1[2], b1[3])};
      *(uint4v*)(bsd + p * 64 * 32) = db;
    }
    __syncthreads();
    short8 af[2], bfr[4];
#pragma unroll
    for (int mi = 0; mi < 2; ++mi)
      af[mi] = *(const short8*)&As[(wm * 32 + mi * 16 + l15) * 32 + quad * 8];
#pragma unroll
    for (int ni = 0; ni < 4; ++ni)
      bfr[ni] = *(const short8*)&Bs[(wn * 64 + ni * 16 + l15) * 32 + quad * 8];
#pragma unroll
    for (int mi = 0; mi < 2; ++mi)
#pragma unroll
      for (int ni = 0; ni < 4; ++ni)
        acc[mi][ni] = __builtin_amdgcn_mfma_f32_16x16x32_bf16(af[mi], bfr[ni], acc[mi][ni], 0, 0, 0);
  }

  float bv[4];
#pragma unroll
  for (int ni = 0; ni < 4; ++ni) bv[ni] = bias[bn * 128 + wn * 64 + ni * 16 + l15];

#pragma unroll
  for (int mi = 0; mi < 2; ++mi) {
    const int mbase = bm * 64 + wm * 32 + mi * 16 + quad * 4;
#pragma unroll
    for (int ni = 0; ni < 4; ++ni) {
      const int n = bn * 128 + wn * 64 + ni * 16 + l15;
#pragma unroll
      for (int r = 0; r < 4; ++r)
        dst[(long)(mbase + r) * 1024 + n] = acc[mi][ni][r] + bv[ni];
    }
  }
}

// ---------------- flash attention: UNCHANGED from R6 (control group: 59.6us) ----------------
__global__ __launch_bounds__(256, 2) void attn_flash(const u16* __restrict__ Q,
                                                     const u16* __restrict__ K,
                                                     const u16* __restrict__ V,
                                                     u16* __restrict__ X) {
  __shared__ u16 KVs[4][64 * 72];  // [0..1] = K dbuf [kv][d] bf16; [2..3] = V^T dbuf [d][kv] fp16
  const int tid = threadIdx.x, w = tid >> 6, l = tid & 63;
  const int l15 = l & 15, quad = l >> 4;
  const int qh = w >> 1, kh = w & 1;  // wave = (q-half, kv-half)

  // XCD-aware swizzle: 512 blocks, 64 per XCD, 4 heads per XCD -> ~2MB K+V working set in L2
  const int bid = blockIdx.x;
  const int xcd = bid & 7, idx = bid >> 3;
  const int qx = idx & 15, bh = xcd + 8 * (idx >> 4);
  const int q0 = qx * 128;

  const u16* qp = Q + (long)bh * 2048 * 64;  // [2048][64] bf16, pre-scaled by 0.125*log2e
  const u16* kp = K + (long)bh * 2048 * 64;  // [2048][64] bf16
  const u16* vp = V + (long)bh * 2048 * 64;  // [64][2048] fp16 (V^T)

  // staging map: thread covers 16B chunks; rows r0 (0..31) and r1 (32..63)
  const int r0 = tid >> 3, c0 = tid & 7, r1 = 32 + (tid >> 3);

  // two register staging sets (A/B by tile parity) so issue(t+2) never clobbers store(t+1)
  short8 skA0, svA0, skA1, svA1, skB0, svB0, skB1, svB1;

#define ISSUE_LOADS_A(kv0) \
    skA0 = *(const short8*)(kp + (long)((kv0) + r0) * 64 + c0 * 8); \
    svA0 = *(const short8*)(vp + (long)r0 * 2048 + (kv0) + c0 * 8); \
    skA1 = *(const short8*)(kp + (long)((kv0) + r1) * 64 + c0 * 8); \
    svA1 = *(const short8*)(vp + (long)r1 * 2048 + (kv0) + c0 * 8);

#define ISSUE_LOADS_B(kv0) \
    skB0 = *(const short8*)(kp + (long)((kv0) + r0) * 64 + c0 * 8); \
    svB0 = *(const short8*)(vp + (long)r0 * 2048 + (kv0) + c0 * 8); \
    skB1 = *(const short8*)(kp + (long)((kv0) + r1) * 64 + c0 * 8); \
    svB1 = *(const short8*)(vp + (long)r1 * 2048 + (kv0) + c0 * 8);

#define STORE_TILE_A(pb_) \
    *(short8*)&KVs[pb_][r0 * 72 + c0 * 8] = skA0; \
    *(short8*)&KVs[2 + (pb_)][r0 * 72 + c0 * 8] = svA0; \
    *(short8*)&KVs[pb_][r1 * 72 + c0 * 8] = skA1; \
    *(short8*)&KVs[2 + (pb_)][r1 * 72 + c0 * 8] = svA1;

#define STORE_TILE_B(pb_) \
    *(short8*)&KVs[pb_][r0 * 72 + c0 * 8] = skB0; \
    *(short8*)&KVs[2 + (pb_)][r0 * 72 + c0 * 8] = svB0; \
    *(short8*)&KVs[pb_][r1 * 72 + c0 * 8] = skB1; \
    *(short8*)&KVs[2 + (pb_)][r1 * 72 + c0 * 8] = svB1;

  // Q fragments (B-operand of S^T = K*Q^T): lane holds Q[q = qh*64+nq*16+l15][d = kc*32+quad*8+j]
  short8 qf[4][2];
#pragma unroll
  for (int nq = 0; nq < 4; ++nq)
#pragma unroll
    for (int kc = 0; kc < 2; ++kc)
      qf[nq][kc] = *(const short8*)(qp + (long)(q0 + qh * 64 + nq * 16 + l15) * 64 + kc * 32 + quad * 8);

  // O^T partial accumulators: o[nq][nd] -> D[row = d = nd*16+quad*4+r][col = q = l15]
  floatx4 o[4][4];
#pragma unroll
  for (int nq = 0; nq < 4; ++nq)
#pragma unroll
    for (int nd = 0; nd < 4; ++nd) o[nq][nd] = (floatx4){0.f, 0.f, 0.f, 0.f};
  float den[4] = {0.f, 0.f, 0.f, 0.f};

  // butterfly lane predicates
  const bool p1 = (l & 32) != 0;
  const bool p3 = (l & 16) != 0;
  const bool p2 = p1 ^ p3;

  // 2-stage register butterfly (R1/R3 HW-verified form): pk[mk][i] (S^T pack:
  // kv_local = mk*16+quad*4+2i+{0,1}) -> pb[dw] = P^T B-frag dword
  // (kv_local = quad*8 + 2dw + {0,1}).
#define BFLY(pbv, m00, m01, m10, m11) { \
    u32 A0 = p1 ? (m10) : (m00), A1 = p1 ? (m11) : (m01); \
    u32 s0_ = p1 ? (m00) : (m10), s1_ = p1 ? (m01) : (m11); \
    u32 B0 = (u32)__shfl_xor((int)s0_, 32), B1 = (u32)__shfl_xor((int)s1_, 32); \
    u32 t0 = p2 ? A0 : B0, t1 = p2 ? A1 : B1; \
    u32 u0 = (u32)__shfl_xor((int)t0, 16), u1 = (u32)__shfl_xor((int)t1, 16); \
    u32 w0 = p2 ? B0 : A0, w1 = p2 ? B1 : A1; \
    pbv[0] = p3 ? u0 : w0; pbv[1] = p3 ? u1 : w1; \
    pbv[2] = p3 ? w0 : u0; pbv[3] = p3 ? w1 : u1; \
  }

#define ATTN_ITER(t, p, IS, ST) { \
    if ((t) < 30) { IS(((t) + 2) * 64) } \
    if ((t) < 31) { ST((p) ^ 1) } \
    const int kr0 = kh * 32 + l15, kr1 = kh * 32 + 16 + l15; \
    short8 ak00 = *(const short8*)&KVs[p][kr0 * 72 + quad * 8]; \
    short8 ak01 = *(const short8*)&KVs[p][kr0 * 72 + 32 + quad * 8]; \
    short8 ak10 = *(const short8*)&KVs[p][kr1 * 72 + quad * 8]; \
    short8 ak11 = *(const short8*)&KVs[p][kr1 * 72 + 32 + quad * 8]; \
    half8 vf0 = *(const half8*)&KVs[2 + (p)][(0 * 16 + l15) * 72 + kh * 32 + quad * 8]; \
    half8 vf1 = *(const half8*)&KVs[2 + (p)][(1 * 16 + l15) * 72 + kh * 32 + quad * 8]; \
    half8 vf2 = *(const half8*)&KVs[2 + (p)][(2 * 16 + l15) * 72 + kh * 32 + quad * 8]; \
    half8 vf3 = *(const half8*)&KVs[2 + (p)][(3 * 16 + l15) * 72 + kh * 32 + quad * 8]; \
    u32 pk[4][2][2]; \
    _Pragma("unroll") \
    for (int nq = 0; nq < 4; ++nq) { \
      floatx4 st0 = (floatx4){0.f, 0.f, 0.f, 0.f}, st1 = (floatx4){0.f, 0.f, 0.f, 0.f}; \
      st0 = __builtin_amdgcn_mfma_f32_16x16x32_bf16(ak00, qf[nq][0], st0, 0, 0, 0); \
      st0 = __builtin_amdgcn_mfma_f32_16x16x32_bf16(ak01, qf[nq][1], st0, 0, 0, 0); \
      st1 = __builtin_amdgcn_mfma_f32_16x16x32_bf16(ak10, qf[nq][0], st1, 0, 0, 0); \
      st1 = __builtin_amdgcn_mfma_f32_16x16x32_bf16(ak11, qf[nq][1], st1, 0, 0, 0); \
      float e0 = fexp2(st0[0]), e1 = fexp2(st0[1]), e2 = fexp2(st0[2]), e3 = fexp2(st0[3]); \
      den[nq] += (e0 + e1) + (e2 + e3); \
      pk[nq][0][0] = pkh(e0, e1); pk[nq][0][1] = pkh(e2, e3); \
      e0 = fexp2(st1[0]); e1 = fexp2(st1[1]); e2 = fexp2(st1[2]); e3 = fexp2(st1[3]); \
      den[nq] += (e0 + e1) + (e2 + e3); \
      pk[nq][1][0] = pkh(e0, e1); pk[nq][1][1] = pkh(e2, e3); \
    } \
    _Pragma("unroll") \
    for (int nq = 0; nq < 4; ++nq) { \
      uint4v pb; \
      BFLY(pb, pk[nq][0][0], pk[nq][0][1], pk[nq][1][0], pk[nq][1][1]) \
      half8 pbs = __builtin_bit_cast(half8, pb); \
      o[nq][0] = __builtin_amdgcn_mfma_f32_16x16x32_f16(vf0, pbs, o[nq][0], 0, 0, 0); \
      o[nq][1] = __builtin_amdgcn_mfma_f32_16x16x32_f16(vf1, pbs, o[nq][1], 0, 0, 0); \
      o[nq][2] = __builtin_amdgcn_mfma_f32_16x16x32_f16(vf2, pbs, o[nq][2], 0, 0, 0); \
      o[nq][3] = __builtin_amdgcn_mfma_f32_16x16x32_f16(vf3, pbs, o[nq][3], 0, 0, 0); \
    } \
    __syncthreads(); \
  }

  // prologue: tile 0 -> set A -> buf0; tile 1 -> set B (in flight across barrier)
  ISSUE_LOADS_A(0)
  STORE_TILE_A(0)
  ISSUE_LOADS_B(64)
  __syncthreads();

  for (int tt = 0; tt < 32; tt += 2) {
    ATTN_ITER(tt, 0, ISSUE_LOADS_A, STORE_TILE_B)
    ATTN_ITER(tt + 1, 1, ISSUE_LOADS_B, STORE_TILE_A)
  }

  // in-wave den reduction: sum quads -> per-lane full kv-half sum for q = l15
  float dsum[4];
#pragma unroll
  for (int nq = 0; nq < 4; ++nq) {
    float d = den[nq];
    d += __shfl_xor(d, 16);
    d += __shfl_xor(d, 32);
    dsum[nq] = d;
  }

  // cross-kv-half merge through the retired K/V LDS (36.9KB >= 32KB O + 0.5KB den)
  float* osc = (float*)KVs;            // [(qh*4+nq)*4+nd][lane] x floatx4  (32KB)
  float* dsc = osc + 8192;             // [(qh*4+nq)*16 + l15]              (0.5KB)
  if (kh == 1) {
#pragma unroll
    for (int nq = 0; nq < 4; ++nq)
#pragma unroll
      for (int nd = 0; nd < 4; ++nd)
        *(floatx4*)&osc[(((qh * 4 + nq) * 4 + nd) * 64 + l) * 4] = o[nq][nd];
    if (l < 16) {
#pragma unroll
      for (int nq = 0; nq < 4; ++nq) dsc[(qh * 4 + nq) * 16 + l] = dsum[nq];
    }
  }
  __syncthreads();

  if (kh == 0) {
    float rcp[4];
#pragma unroll
    for (int nq = 0; nq < 4; ++nq) rcp[nq] = 1.0f / (dsum[nq] + dsc[(qh * 4 + nq) * 16 + l15]);
    const int b = bh >> 4, h = bh & 15;
#pragma unroll
    for (int nq = 0; nq < 4; ++nq) {
      const int s = q0 + qh * 64 + nq * 16 + l15;
      u16* xrow = X + ((long)(b * 2048 + s)) * 1024 + h * 64;
#pragma unroll
      for (int nd = 0; nd < 4; ++nd) {
        floatx4 om = o[nq][nd] + *(const floatx4*)&osc[(((qh * 4 + nq) * 4 + nd) * 64 + l) * 4];
        ushortx4 u;
#pragma unroll
        for (int r = 0; r < 4; ++r) u[r] = f2bf(om[r] * rcp[nq]);
        *(ushortx4*)&xrow[nd * 16 + quad * 4] = u;
      }
    }
  }
}

extern "C" void kernel_launch(void* const* d_in, const int* in_sizes, int n_in,
                              void* d_out, int out_size, void* d_ws, size_t ws_size,
                              hipStream_t stream) {
  u16* ws = (u16*)d_ws;
  const size_t M4 = 4194304;
  u16* Qb = ws;                 // [32][2048][64] bf16, q*0.125*log2e
  u16* Kb = ws + M4;            // [32][2048][64] bf16
  u16* Vb = ws + 2 * M4;        // [32][64][2048] fp16 (V^T)
  u16* Xb = ws + 3 * M4;        // [4096][1024] bf16 attn output

  // d_in: 0=query 1=key 2=value 3=Wq 4=bq 5=Wk 6=bk 7=Wv 8=bv 9=Wo 10=bo (all fp32)
  GemmArg gq{(const float*)d_in[0], (const float*)d_in[3], (const float*)d_in[4], Qb, 0};
  GemmArg gk{(const float*)d_in[1], (const float*)d_in[5], (const float*)d_in[6], Kb, 1};
  GemmArg gv{(const float*)d_in[2], (const float*)d_in[7], (const float*)d_in[8], Vb, 2};
  gemm_qkv<<<dim3(768), 256, 0, stream>>>(gq, gk, gv);

  attn_flash<<<dim3(512), 256, 0, stream>>>(Qb, Kb, Vb, Xb);

  gemm_o<<<dim3(512), 256, 0, stream>>>(Xb, (const float*)d_in[9], (const float*)d_in[10],
                                        (float*)d_out);
}

// Round 8
// 220.959 us; speedup vs baseline: 1.2244x; 1.2244x over previous
//
#include <hip/hip_runtime.h>

typedef unsigned short u16;
typedef unsigned int u32;
typedef __attribute__((ext_vector_type(8))) short short8;
typedef __attribute__((ext_vector_type(8))) _Float16 half8;
typedef __attribute__((ext_vector_type(4))) float floatx4;
typedef __attribute__((ext_vector_type(4))) unsigned short ushortx4;
typedef __attribute__((ext_vector_type(4))) unsigned int uint4v;

#define DEV static __device__ __forceinline__

DEV float bf2f(u16 u) { union { unsigned u; float f; } v; v.u = ((unsigned)u) << 16; return v.f; }
DEV u16 f2bf(float f) {
  union { float f; unsigned u; } v; v.f = f;
  return (u16)((v.u + 0x7FFFu + ((v.u >> 16) & 1u)) >> 16);  // RNE; finite inputs
}
DEV u16 f2h(float f) { return __builtin_bit_cast(u16, (_Float16)f); }  // v_cvt_f16_f32 (RNE)
// pack two floats to two fp16 in one v_cvt_pkrtz_f16_f32: a -> low u16, b -> high u16
DEV u32 pkh(float a, float b) {
  return __builtin_bit_cast(u32, __builtin_amdgcn_cvt_pkrtz(a, b));
}
DEV float fexp2(float x) { return __builtin_amdgcn_exp2f(x); }  // v_exp_f32

// async global->LDS, 16B/lane, LDS dest = wave-uniform base + lane*16 (m97-proven form)
#define GLDS(g, l) __builtin_amdgcn_global_load_lds( \
    (const __attribute__((address_space(1))) void*)(g), \
    (__attribute__((address_space(3))) void*)(l), 16, 0, 0)

// ---------------- fp32 -> bf16 conversion of all 11 inputs ----------------
// R8: restored. R7 proved this is a cache-warming + 2x-compression pass: GEMM staging
// loads then hit L2-resident bf16 (~200cy) instead of HBM fp32 (~900cy, fully exposed
// in the serial K-loop -> gemm_qkv 130us vs ~55us).
struct CvtArg {
  const float* src[11];
  u16* dst[11];
  int cum[12];
};

__global__ void convert(CvtArg a) {
  const long base = ((long)blockIdx.x * 256 + threadIdx.x) * 4;
  if (base >= a.cum[11]) return;
  int s = 0;
  while (s < 10 && base >= a.cum[s + 1]) ++s;
  const long off = base - a.cum[s];
  const float* sp = a.src[s] + off;
  ushortx4 u;
#pragma unroll
  for (int r = 0; r < 4; ++r) u[r] = f2bf(sp[r]);
  *(ushortx4*)(a.dst[s] + off) = u;
}

// ---------------- projection GEMMs (m97 structure; R6-proven) ----------------
struct GemmArg {
  const u16* x;    // [4096][1024] bf16
  const u16* w;    // [1024][1024] bf16 (torch: y = x @ W.T + b -> NT gemm)
  const u16* bias; // [1024] bf16
  u16* dst;
  int mode;        // 0=Q (BHSD, *0.125*log2e)  1=K (BHSD)  2=V^T fp16 (BHDS)
};

__global__ __launch_bounds__(256, 2) void gemm_nt(GemmArg g0, GemmArg g1, GemmArg g2) {
  GemmArg g = (blockIdx.z == 0) ? g0 : ((blockIdx.z == 1) ? g1 : g2);
  __shared__ u16 As[128 * 32];
  __shared__ u16 Bs[128 * 32];
  const int tid = threadIdx.x, w = tid >> 6, l = tid & 63;
  const int l15 = l & 15, quad = l >> 4;
  const int bm = blockIdx.x, bn = blockIdx.y;
  const int wm = w >> 1, wn = w & 1;

  floatx4 acc[4][4];
#pragma unroll
  for (int i = 0; i < 4; ++i)
#pragma unroll
    for (int j = 0; j < 4; ++j) acc[i][j] = (floatx4){0.f, 0.f, 0.f, 0.f};

  const u16* xb = g.x + (long)(bm * 128 + w * 16 + (l >> 2)) * 1024 + (l & 3) * 8;
  const u16* wb = g.w + (long)(bn * 128 + w * 16 + (l >> 2)) * 1024 + (l & 3) * 8;
  u16* asb = &As[(w * 16) * 32];
  u16* bsb = &Bs[(w * 16) * 32];

  for (int kt = 0; kt < 32; ++kt) {
    const int k0 = kt * 32;
    __syncthreads();
#pragma unroll
    for (int p = 0; p < 2; ++p) {
      GLDS(xb + (long)p * 64 * 1024 + k0, asb + p * 64 * 32);
      GLDS(wb + (long)p * 64 * 1024 + k0, bsb + p * 64 * 32);
    }
    __syncthreads();
    short8 af[4], bfr[4];
#pragma unroll
    for (int mi = 0; mi < 4; ++mi)
      af[mi] = *(const short8*)&As[(wm * 64 + mi * 16 + l15) * 32 + quad * 8];
#pragma unroll
    for (int ni = 0; ni < 4; ++ni)
      bfr[ni] = *(const short8*)&Bs[(wn * 64 + ni * 16 + l15) * 32 + quad * 8];
#pragma unroll
    for (int mi = 0; mi < 4; ++mi)
#pragma unroll
      for (int ni = 0; ni < 4; ++ni)
        acc[mi][ni] = __builtin_amdgcn_mfma_f32_16x16x32_bf16(af[mi], bfr[ni], acc[mi][ni], 0, 0, 0);
  }

  float bv[4];
#pragma unroll
  for (int ni = 0; ni < 4; ++ni) bv[ni] = bf2f(g.bias[bn * 128 + wn * 64 + ni * 16 + l15]);

  // C/D layout: col = lane&15, row = quad*4 + reg  [m89/m91]
#pragma unroll
  for (int mi = 0; mi < 4; ++mi) {
    const int mbase = bm * 128 + wm * 64 + mi * 16 + quad * 4;
#pragma unroll
    for (int ni = 0; ni < 4; ++ni) {
      const int n = bn * 128 + wn * 64 + ni * 16 + l15;
      if (g.mode == 2) {  // V^T [B,H,64,2048] in fp16 (feeds f16 PV MFMA)
        const int b = mbase >> 11, s = mbase & 2047;
        const int h = n >> 6, d = n & 63;
        ushortx4 u;
#pragma unroll
        for (int r = 0; r < 4; ++r) u[r] = f2h(acc[mi][ni][r] + bv[ni]);
        *(ushortx4*)&g.dst[((long)(b * 16 + h) * 64 + d) * 2048 + s] = u;
      } else {  // Q/K -> [B,H,2048,64]; Q folds 1/sqrt(64) * log2(e) for exp2 softmax
        const float sc = (g.mode == 0) ? 0.18033688011f : 1.0f;
        const int h = n >> 6, d = n & 63;
#pragma unroll
        for (int r = 0; r < 4; ++r) {
          const int m = mbase + r, b = m >> 11, s = m & 2047;
          g.dst[((long)(b * 16 + h) * 2048 + s) * 64 + d] = f2bf((acc[mi][ni][r] + bv[ni]) * sc);
        }
      }
    }
  }
}

// ---------------- output GEMM: 64x128 tile, 512 blocks = 2 blocks/CU ----------------
// R8: the ONLY change kept from R7's bundle. R6's o-proj ran 256 blocks = 1 block/CU:
// no second block to cover the barrier drain (m114 mechanism absent). BM=64 doubles the
// grid. Both operands bf16 via GLDS (A = Xb, B = NWO — both L2-warm from producers).
// XCD swizzle: each XCD pins one 256KB Wo panel while A streams.
__global__ __launch_bounds__(256, 2) void gemm_o(const u16* __restrict__ x,
                                                 const u16* __restrict__ wo,
                                                 const u16* __restrict__ bias,
                                                 float* __restrict__ dst) {
  const int bid = blockIdx.x;
  const int gidx = (bid & 7) * 64 + (bid >> 3);   // 512 % 8 == 0: bijective
  const int bm = gidx & 63;                       // bm fastest within an XCD chunk
  const int bn = gidx >> 6;

  __shared__ u16 As[64 * 32];
  __shared__ u16 Bs[128 * 32];
  const int tid = threadIdx.x, w = tid >> 6, l = tid & 63;
  const int l15 = l & 15, quad = l >> 4;
  const int wm = w >> 1, wn = w & 1;   // wave tile: 32m x 64n

  floatx4 acc[2][4];
#pragma unroll
  for (int i = 0; i < 2; ++i)
#pragma unroll
    for (int j = 0; j < 4; ++j) acc[i][j] = (floatx4){0.f, 0.f, 0.f, 0.f};

  const u16* xb = x + (long)(bm * 64 + w * 16 + (l >> 2)) * 1024 + (l & 3) * 8;
  const u16* wb = wo + (long)(bn * 128 + w * 16 + (l >> 2)) * 1024 + (l & 3) * 8;
  u16* asb = &As[(w * 16) * 32];
  u16* bsb = &Bs[(w * 16) * 32];

  for (int kt = 0; kt < 32; ++kt) {
    const int k0 = kt * 32;
    __syncthreads();
    GLDS(xb + k0, asb);
#pragma unroll
    for (int p = 0; p < 2; ++p)
      GLDS(wb + (long)p * 64 * 1024 + k0, bsb + p * 64 * 32);
    __syncthreads();
    short8 af[2], bfr[4];
#pragma unroll
    for (int mi = 0; mi < 2; ++mi)
      af[mi] = *(const short8*)&As[(wm * 32 + mi * 16 + l15) * 32 + quad * 8];
#pragma unroll
    for (int ni = 0; ni < 4; ++ni)
      bfr[ni] = *(const short8*)&Bs[(wn * 64 + ni * 16 + l15) * 32 + quad * 8];
#pragma unroll
    for (int mi = 0; mi < 2; ++mi)
#pragma unroll
      for (int ni = 0; ni < 4; ++ni)
        acc[mi][ni] = __builtin_amdgcn_mfma_f32_16x16x32_bf16(af[mi], bfr[ni], acc[mi][ni], 0, 0, 0);
  }

  float bv[4];
#pragma unroll
  for (int ni = 0; ni < 4; ++ni) bv[ni] = bf2f(bias[bn * 128 + wn * 64 + ni * 16 + l15]);

#pragma unroll
  for (int mi = 0; mi < 2; ++mi) {
    const int mbase = bm * 64 + wm * 32 + mi * 16 + quad * 4;
#pragma unroll
    for (int ni = 0; ni < 4; ++ni) {
      const int n = bn * 128 + wn * 64 + ni * 16 + l15;
#pragma unroll
      for (int r = 0; r < 4; ++r)
        dst[(long)(mbase + r) * 1024 + n] = acc[mi][ni][r] + bv[ni];
    }
  }
}

// ---------------- flash attention: UNCHANGED from R6 (control group: 59.6us) ----------------
__global__ __launch_bounds__(256, 2) void attn_flash(const u16* __restrict__ Q,
                                                     const u16* __restrict__ K,
                                                     const u16* __restrict__ V,
                                                     u16* __restrict__ X) {
  __shared__ u16 KVs[4][64 * 72];  // [0..1] = K dbuf [kv][d] bf16; [2..3] = V^T dbuf [d][kv] fp16
  const int tid = threadIdx.x, w = tid >> 6, l = tid & 63;
  const int l15 = l & 15, quad = l >> 4;
  const int qh = w >> 1, kh = w & 1;  // wave = (q-half, kv-half)

  // XCD-aware swizzle: 512 blocks, 64 per XCD, 4 heads per XCD -> ~2MB K+V working set in L2
  const int bid = blockIdx.x;
  const int xcd = bid & 7, idx = bid >> 3;
  const int qx = idx & 15, bh = xcd + 8 * (idx >> 4);
  const int q0 = qx * 128;

  const u16* qp = Q + (long)bh * 2048 * 64;  // [2048][64] bf16, pre-scaled by 0.125*log2e
  const u16* kp = K + (long)bh * 2048 * 64;  // [2048][64] bf16
  const u16* vp = V + (long)bh * 2048 * 64;  // [64][2048] fp16 (V^T)

  // staging map: thread covers 16B chunks; rows r0 (0..31) and r1 (32..63)
  const int r0 = tid >> 3, c0 = tid & 7, r1 = 32 + (tid >> 3);

  // two register staging sets (A/B by tile parity) so issue(t+2) never clobbers store(t+1)
  short8 skA0, svA0, skA1, svA1, skB0, svB0, skB1, svB1;

#define ISSUE_LOADS_A(kv0) \
    skA0 = *(const short8*)(kp + (long)((kv0) + r0) * 64 + c0 * 8); \
    svA0 = *(const short8*)(vp + (long)r0 * 2048 + (kv0) + c0 * 8); \
    skA1 = *(const short8*)(kp + (long)((kv0) + r1) * 64 + c0 * 8); \
    svA1 = *(const short8*)(vp + (long)r1 * 2048 + (kv0) + c0 * 8);

#define ISSUE_LOADS_B(kv0) \
    skB0 = *(const short8*)(kp + (long)((kv0) + r0) * 64 + c0 * 8); \
    svB0 = *(const short8*)(vp + (long)r0 * 2048 + (kv0) + c0 * 8); \
    skB1 = *(const short8*)(kp + (long)((kv0) + r1) * 64 + c0 * 8); \
    svB1 = *(const short8*)(vp + (long)r1 * 2048 + (kv0) + c0 * 8);

#define STORE_TILE_A(pb_) \
    *(short8*)&KVs[pb_][r0 * 72 + c0 * 8] = skA0; \
    *(short8*)&KVs[2 + (pb_)][r0 * 72 + c0 * 8] = svA0; \
    *(short8*)&KVs[pb_][r1 * 72 + c0 * 8] = skA1; \
    *(short8*)&KVs[2 + (pb_)][r1 * 72 + c0 * 8] = svA1;

#define STORE_TILE_B(pb_) \
    *(short8*)&KVs[pb_][r0 * 72 + c0 * 8] = skB0; \
    *(short8*)&KVs[2 + (pb_)][r0 * 72 + c0 * 8] = svB0; \
    *(short8*)&KVs[pb_][r1 * 72 + c0 * 8] = skB1; \
    *(short8*)&KVs[2 + (pb_)][r1 * 72 + c0 * 8] = svB1;

  // Q fragments (B-operand of S^T = K*Q^T): lane holds Q[q = qh*64+nq*16+l15][d = kc*32+quad*8+j]
  short8 qf[4][2];
#pragma unroll
  for (int nq = 0; nq < 4; ++nq)
#pragma unroll
    for (int kc = 0; kc < 2; ++kc)
      qf[nq][kc] = *(const short8*)(qp + (long)(q0 + qh * 64 + nq * 16 + l15) * 64 + kc * 32 + quad * 8);

  // O^T partial accumulators: o[nq][nd] -> D[row = d = nd*16+quad*4+r][col = q = l15]
  floatx4 o[4][4];
#pragma unroll
  for (int nq = 0; nq < 4; ++nq)
#pragma unroll
    for (int nd = 0; nd < 4; ++nd) o[nq][nd] = (floatx4){0.f, 0.f, 0.f, 0.f};
  float den[4] = {0.f, 0.f, 0.f, 0.f};

  // butterfly lane predicates
  const bool p1 = (l & 32) != 0;
  const bool p3 = (l & 16) != 0;
  const bool p2 = p1 ^ p3;

  // 2-stage register butterfly (R1/R3 HW-verified form): pk[mk][i] (S^T pack:
  // kv_local = mk*16+quad*4+2i+{0,1}) -> pb[dw] = P^T B-frag dword
  // (kv_local = quad*8 + 2dw + {0,1}).
#define BFLY(pbv, m00, m01, m10, m11) { \
    u32 A0 = p1 ? (m10) : (m00), A1 = p1 ? (m11) : (m01); \
    u32 s0_ = p1 ? (m00) : (m10), s1_ = p1 ? (m01) : (m11); \
    u32 B0 = (u32)__shfl_xor((int)s0_, 32), B1 = (u32)__shfl_xor((int)s1_, 32); \
    u32 t0 = p2 ? A0 : B0, t1 = p2 ? A1 : B1; \
    u32 u0 = (u32)__shfl_xor((int)t0, 16), u1 = (u32)__shfl_xor((int)t1, 16); \
    u32 w0 = p2 ? B0 : A0, w1 = p2 ? B1 : A1; \
    pbv[0] = p3 ? u0 : w0; pbv[1] = p3 ? u1 : w1; \
    pbv[2] = p3 ? w0 : u0; pbv[3] = p3 ? w1 : u1; \
  }

#define ATTN_ITER(t, p, IS, ST) { \
    if ((t) < 30) { IS(((t) + 2) * 64) } \
    if ((t) < 31) { ST((p) ^ 1) } \
    const int kr0 = kh * 32 + l15, kr1 = kh * 32 + 16 + l15; \
    short8 ak00 = *(const short8*)&KVs[p][kr0 * 72 + quad * 8]; \
    short8 ak01 = *(const short8*)&KVs[p][kr0 * 72 + 32 + quad * 8]; \
    short8 ak10 = *(const short8*)&KVs[p][kr1 * 72 + quad * 8]; \
    short8 ak11 = *(const short8*)&KVs[p][kr1 * 72 + 32 + quad * 8]; \
    half8 vf0 = *(const half8*)&KVs[2 + (p)][(0 * 16 + l15) * 72 + kh * 32 + quad * 8]; \
    half8 vf1 = *(const half8*)&KVs[2 + (p)][(1 * 16 + l15) * 72 + kh * 32 + quad * 8]; \
    half8 vf2 = *(const half8*)&KVs[2 + (p)][(2 * 16 + l15) * 72 + kh * 32 + quad * 8]; \
    half8 vf3 = *(const half8*)&KVs[2 + (p)][(3 * 16 + l15) * 72 + kh * 32 + quad * 8]; \
    u32 pk[4][2][2]; \
    _Pragma("unroll") \
    for (int nq = 0; nq < 4; ++nq) { \
      floatx4 st0 = (floatx4){0.f, 0.f, 0.f, 0.f}, st1 = (floatx4){0.f, 0.f, 0.f, 0.f}; \
      st0 = __builtin_amdgcn_mfma_f32_16x16x32_bf16(ak00, qf[nq][0], st0, 0, 0, 0); \
      st0 = __builtin_amdgcn_mfma_f32_16x16x32_bf16(ak01, qf[nq][1], st0, 0, 0, 0); \
      st1 = __builtin_amdgcn_mfma_f32_16x16x32_bf16(ak10, qf[nq][0], st1, 0, 0, 0); \
      st1 = __builtin_amdgcn_mfma_f32_16x16x32_bf16(ak11, qf[nq][1], st1, 0, 0, 0); \
      float e0 = fexp2(st0[0]), e1 = fexp2(st0[1]), e2 = fexp2(st0[2]), e3 = fexp2(st0[3]); \
      den[nq] += (e0 + e1) + (e2 + e3); \
      pk[nq][0][0] = pkh(e0, e1); pk[nq][0][1] = pkh(e2, e3); \
      e0 = fexp2(st1[0]); e1 = fexp2(st1[1]); e2 = fexp2(st1[2]); e3 = fexp2(st1[3]); \
      den[nq] += (e0 + e1) + (e2 + e3); \
      pk[nq][1][0] = pkh(e0, e1); pk[nq][1][1] = pkh(e2, e3); \
    } \
    _Pragma("unroll") \
    for (int nq = 0; nq < 4; ++nq) { \
      uint4v pb; \
      BFLY(pb, pk[nq][0][0], pk[nq][0][1], pk[nq][1][0], pk[nq][1][1]) \
      half8 pbs = __builtin_bit_cast(half8, pb); \
      o[nq][0] = __builtin_amdgcn_mfma_f32_16x16x32_f16(vf0, pbs, o[nq][0], 0, 0, 0); \
      o[nq][1] = __builtin_amdgcn_mfma_f32_16x16x32_f16(vf1, pbs, o[nq][1], 0, 0, 0); \
      o[nq][2] = __builtin_amdgcn_mfma_f32_16x16x32_f16(vf2, pbs, o[nq][2], 0, 0, 0); \
      o[nq][3] = __builtin_amdgcn_mfma_f32_16x16x32_f16(vf3, pbs, o[nq][3], 0, 0, 0); \
    } \
    __syncthreads(); \
  }

  // prologue: tile 0 -> set A -> buf0; tile 1 -> set B (in flight across barrier)
  ISSUE_LOADS_A(0)
  STORE_TILE_A(0)
  ISSUE_LOADS_B(64)
  __syncthreads();

  for (int tt = 0; tt < 32; tt += 2) {
    ATTN_ITER(tt, 0, ISSUE_LOADS_A, STORE_TILE_B)
    ATTN_ITER(tt + 1, 1, ISSUE_LOADS_B, STORE_TILE_A)
  }

  // in-wave den reduction: sum quads -> per-lane full kv-half sum for q = l15
  float dsum[4];
#pragma unroll
  for (int nq = 0; nq < 4; ++nq) {
    float d = den[nq];
    d += __shfl_xor(d, 16);
    d += __shfl_xor(d, 32);
    dsum[nq] = d;
  }

  // cross-kv-half merge through the retired K/V LDS (36.9KB >= 32KB O + 0.5KB den)
  float* osc = (float*)KVs;            // [(qh*4+nq)*4+nd][lane] x floatx4  (32KB)
  float* dsc = osc + 8192;             // [(qh*4+nq)*16 + l15]              (0.5KB)
  if (kh == 1) {
#pragma unroll
    for (int nq = 0; nq < 4; ++nq)
#pragma unroll
      for (int nd = 0; nd < 4; ++nd)
        *(floatx4*)&osc[(((qh * 4 + nq) * 4 + nd) * 64 + l) * 4] = o[nq][nd];
    if (l < 16) {
#pragma unroll
      for (int nq = 0; nq < 4; ++nq) dsc[(qh * 4 + nq) * 16 + l] = dsum[nq];
    }
  }
  __syncthreads();

  if (kh == 0) {
    float rcp[4];
#pragma unroll
    for (int nq = 0; nq < 4; ++nq) rcp[nq] = 1.0f / (dsum[nq] + dsc[(qh * 4 + nq) * 16 + l15]);
    const int b = bh >> 4, h = bh & 15;
#pragma unroll
    for (int nq = 0; nq < 4; ++nq) {
      const int s = q0 + qh * 64 + nq * 16 + l15;
      u16* xrow = X + ((long)(b * 2048 + s)) * 1024 + h * 64;
#pragma unroll
      for (int nd = 0; nd < 4; ++nd) {
        floatx4 om = o[nq][nd] + *(const floatx4*)&osc[(((qh * 4 + nq) * 4 + nd) * 64 + l) * 4];
        ushortx4 u;
#pragma unroll
        for (int r = 0; r < 4; ++r) u[r] = f2bf(om[r] * rcp[nq]);
        *(ushortx4*)&xrow[nd * 16 + quad * 4] = u;
      }
    }
  }
}

extern "C" void kernel_launch(void* const* d_in, const int* in_sizes, int n_in,
                              void* d_out, int out_size, void* d_ws, size_t ws_size,
                              hipStream_t stream) {
  u16* ws = (u16*)d_ws;
  const size_t M1 = 1048576, M4 = 4194304;
  u16* NQ  = ws;                    // bf16 copies of fp32 inputs (NQ reused as Xb)
  u16* NK  = ws + M4;
  u16* NV  = ws + 2 * M4;
  u16* NWQ = ws + 3 * M4;
  u16* NWK = ws + 3 * M4 + M1;
  u16* NWV = ws + 3 * M4 + 2 * M1;
  u16* NWO = ws + 3 * M4 + 3 * M1;
  u16* NBQ = ws + 3 * M4 + 4 * M1;
  u16* NBK = NBQ + 1024;
  u16* NBV = NBQ + 2048;
  u16* NBO = NBQ + 3072;
  u16* Qb = ws + 16 * M1 + 8192;    // [32][2048][64] bf16, q*0.125*log2e
  u16* Kb = Qb + M4;                // [32][2048][64] bf16
  u16* Vb = Qb + 2 * M4;            // [32][64][2048] fp16 (V^T)
  u16* Xb = NQ;                     // [4096][1024] bf16

  CvtArg ca;
  u16* dsts[11] = {NQ, NK, NV, NWQ, NBQ, NWK, NBK, NWV, NBV, NWO, NBO};
  int sizes[11] = {(int)M4, (int)M4, (int)M4, (int)M1, 1024, (int)M1, 1024, (int)M1, 1024, (int)M1, 1024};
  int c = 0;
  for (int i = 0; i < 11; ++i) {
    ca.src[i] = (const float*)d_in[i];
    ca.dst[i] = dsts[i];
    ca.cum[i] = c;
    c += sizes[i];
  }
  ca.cum[11] = c;
  convert<<<(c / 4 + 255) / 256, 256, 0, stream>>>(ca);

  GemmArg gq{NQ, NWQ, NBQ, Qb, 0};
  GemmArg gk{NK, NWK, NBK, Kb, 1};
  GemmArg gv{NV, NWV, NBV, Vb, 2};
  gemm_nt<<<dim3(32, 8, 3), 256, 0, stream>>>(gq, gk, gv);

  attn_flash<<<dim3(512), 256, 0, stream>>>(Qb, Kb, Vb, Xb);

  gemm_o<<<dim3(512), 256, 0, stream>>>(Xb, NWO, NBO, (float*)d_out);
}

// Round 9
// 218.764 us; speedup vs baseline: 1.2367x; 1.0100x over previous
//
#include <hip/hip_runtime.h>

typedef unsigned short u16;
typedef unsigned int u32;
typedef __attribute__((ext_vector_type(8))) short short8;
typedef __attribute__((ext_vector_type(8))) _Float16 half8;
typedef __attribute__((ext_vector_type(4))) float floatx4;
typedef __attribute__((ext_vector_type(4))) unsigned short ushortx4;
typedef __attribute__((ext_vector_type(4))) unsigned int uint4v;

#define DEV static __device__ __forceinline__

DEV float bf2f(u16 u) { union { unsigned u; float f; } v; v.u = ((unsigned)u) << 16; return v.f; }
DEV u16 f2bf(float f) {
  union { float f; unsigned u; } v; v.f = f;
  return (u16)((v.u + 0x7FFFu + ((v.u >> 16) & 1u)) >> 16);  // RNE; finite inputs
}
DEV u16 f2h(float f) { return __builtin_bit_cast(u16, (_Float16)f); }  // v_cvt_f16_f32 (RNE)
// pack two floats to two fp16 in one v_cvt_pkrtz_f16_f32: a -> low u16, b -> high u16
DEV u32 pkh(float a, float b) {
  return __builtin_bit_cast(u32, __builtin_amdgcn_cvt_pkrtz(a, b));
}
DEV float fexp2(float x) { return __builtin_amdgcn_exp2f(x); }  // v_exp_f32

// async global->LDS, 16B/lane, LDS dest = wave-uniform base + lane*16 (m97-proven form)
#define GLDS(g, l) __builtin_amdgcn_global_load_lds( \
    (const __attribute__((address_space(1))) void*)(g), \
    (__attribute__((address_space(3))) void*)(l), 16, 0, 0)

// ---------------- fp32 -> bf16 conversion of all 11 inputs ----------------
// R8 proved this is a cache-warming + 2x-compression pass: GEMM staging loads hit
// L2-resident bf16 (~200cy) instead of HBM fp32 (~900cy exposed in the K-loop).
struct CvtArg {
  const float* src[11];
  u16* dst[11];
  int cum[12];
};

__global__ void convert(CvtArg a) {
  const long base = ((long)blockIdx.x * 256 + threadIdx.x) * 4;
  if (base >= a.cum[11]) return;
  int s = 0;
  while (s < 10 && base >= a.cum[s + 1]) ++s;
  const long off = base - a.cum[s];
  const float* sp = a.src[s] + off;
  ushortx4 u;
#pragma unroll
  for (int r = 0; r < 4; ++r) u[r] = f2bf(sp[r]);
  *(ushortx4*)(a.dst[s] + off) = u;
}

// ---------------- projection GEMMs: BK=64 via two kc-subtiles ----------------
// R9: halve the barrier count (32 -> 16 K-iterations). LDS = [kc][128][32] — two
// copies of the PROVEN BK=32 layout, so GLDS dest arithmetic, fragment addressing,
// and bank behavior are bit-identical to R8; only the loop geometry changes.
// Per-block vmcnt(0)+barrier drains halve (m135: 156-332cy each).
struct GemmArg {
  const u16* x;    // [4096][1024] bf16
  const u16* w;    // [1024][1024] bf16 (torch: y = x @ W.T + b -> NT gemm)
  const u16* bias; // [1024] bf16
  u16* dst;
  int mode;        // 0=Q (BHSD, *0.125*log2e)  1=K (BHSD)  2=V^T fp16 (BHDS)
};

__global__ __launch_bounds__(256, 2) void gemm_nt(GemmArg g0, GemmArg g1, GemmArg g2) {
  GemmArg g = (blockIdx.z == 0) ? g0 : ((blockIdx.z == 1) ? g1 : g2);
  __shared__ u16 As[2][128 * 32];
  __shared__ u16 Bs[2][128 * 32];
  const int tid = threadIdx.x, w = tid >> 6, l = tid & 63;
  const int l15 = l & 15, quad = l >> 4;
  const int bm = blockIdx.x, bn = blockIdx.y;
  const int wm = w >> 1, wn = w & 1;

  floatx4 acc[4][4];
#pragma unroll
  for (int i = 0; i < 4; ++i)
#pragma unroll
    for (int j = 0; j < 4; ++j) acc[i][j] = (floatx4){0.f, 0.f, 0.f, 0.f};

  const u16* xb = g.x + (long)(bm * 128 + w * 16 + (l >> 2)) * 1024 + (l & 3) * 8;
  const u16* wb = g.w + (long)(bn * 128 + w * 16 + (l >> 2)) * 1024 + (l & 3) * 8;
  const int sbo = (w * 16) * 32;  // per-wave staging base within a kc-subtile

  for (int kt = 0; kt < 16; ++kt) {
    const int k0 = kt * 64;
    __syncthreads();
#pragma unroll
    for (int kc = 0; kc < 2; ++kc) {
#pragma unroll
      for (int p = 0; p < 2; ++p) {
        GLDS(xb + (long)p * 64 * 1024 + k0 + kc * 32, &As[kc][sbo + p * 64 * 32]);
        GLDS(wb + (long)p * 64 * 1024 + k0 + kc * 32, &Bs[kc][sbo + p * 64 * 32]);
      }
    }
    __syncthreads();
#pragma unroll
    for (int kc = 0; kc < 2; ++kc) {
      short8 af[4], bfr[4];
#pragma unroll
      for (int mi = 0; mi < 4; ++mi)
        af[mi] = *(const short8*)&As[kc][(wm * 64 + mi * 16 + l15) * 32 + quad * 8];
#pragma unroll
      for (int ni = 0; ni < 4; ++ni)
        bfr[ni] = *(const short8*)&Bs[kc][(wn * 64 + ni * 16 + l15) * 32 + quad * 8];
#pragma unroll
      for (int mi = 0; mi < 4; ++mi)
#pragma unroll
        for (int ni = 0; ni < 4; ++ni)
          acc[mi][ni] = __builtin_amdgcn_mfma_f32_16x16x32_bf16(af[mi], bfr[ni], acc[mi][ni], 0, 0, 0);
    }
  }

  float bv[4];
#pragma unroll
  for (int ni = 0; ni < 4; ++ni) bv[ni] = bf2f(g.bias[bn * 128 + wn * 64 + ni * 16 + l15]);

  // C/D layout: col = lane&15, row = quad*4 + reg  [m89/m91]
#pragma unroll
  for (int mi = 0; mi < 4; ++mi) {
    const int mbase = bm * 128 + wm * 64 + mi * 16 + quad * 4;
#pragma unroll
    for (int ni = 0; ni < 4; ++ni) {
      const int n = bn * 128 + wn * 64 + ni * 16 + l15;
      if (g.mode == 2) {  // V^T [B,H,64,2048] in fp16 (feeds f16 PV MFMA)
        const int b = mbase >> 11, s = mbase & 2047;
        const int h = n >> 6, d = n & 63;
        ushortx4 u;
#pragma unroll
        for (int r = 0; r < 4; ++r) u[r] = f2h(acc[mi][ni][r] + bv[ni]);
        *(ushortx4*)&g.dst[((long)(b * 16 + h) * 64 + d) * 2048 + s] = u;
      } else {  // Q/K -> [B,H,2048,64]; Q folds 1/sqrt(64) * log2(e) for exp2 softmax
        const float sc = (g.mode == 0) ? 0.18033688011f : 1.0f;
        const int h = n >> 6, d = n & 63;
#pragma unroll
        for (int r = 0; r < 4; ++r) {
          const int m = mbase + r, b = m >> 11, s = m & 2047;
          g.dst[((long)(b * 16 + h) * 2048 + s) * 64 + d] = f2bf((acc[mi][ni][r] + bv[ni]) * sc);
        }
      }
    }
  }
}

// ---------------- output GEMM: 64x128 tile, 512 blocks, BK=64 kc-subtiles ----------------
// R8's grid fix kept (2 blocks/CU, m114 overlap). R9 adds the same barrier-halving:
// 16 K-iterations, LDS [kc][rows][32] twin-subtile layout, 6 GLDS/iter.
__global__ __launch_bounds__(256, 2) void gemm_o(const u16* __restrict__ x,
                                                 const u16* __restrict__ wo,
                                                 const u16* __restrict__ bias,
                                                 float* __restrict__ dst) {
  const int bid = blockIdx.x;
  const int gidx = (bid & 7) * 64 + (bid >> 3);   // 512 % 8 == 0: bijective
  const int bm = gidx & 63;                       // bm fastest within an XCD chunk
  const int bn = gidx >> 6;

  __shared__ u16 As[2][64 * 32];
  __shared__ u16 Bs[2][128 * 32];
  const int tid = threadIdx.x, w = tid >> 6, l = tid & 63;
  const int l15 = l & 15, quad = l >> 4;
  const int wm = w >> 1, wn = w & 1;   // wave tile: 32m x 64n

  floatx4 acc[2][4];
#pragma unroll
  for (int i = 0; i < 2; ++i)
#pragma unroll
    for (int j = 0; j < 4; ++j) acc[i][j] = (floatx4){0.f, 0.f, 0.f, 0.f};

  const u16* xb = x + (long)(bm * 64 + w * 16 + (l >> 2)) * 1024 + (l & 3) * 8;
  const u16* wb = wo + (long)(bn * 128 + w * 16 + (l >> 2)) * 1024 + (l & 3) * 8;
  const int sbo = (w * 16) * 32;

  for (int kt = 0; kt < 16; ++kt) {
    const int k0 = kt * 64;
    __syncthreads();
#pragma unroll
    for (int kc = 0; kc < 2; ++kc) {
      GLDS(xb + k0 + kc * 32, &As[kc][sbo]);
#pragma unroll
      for (int p = 0; p < 2; ++p)
        GLDS(wb + (long)p * 64 * 1024 + k0 + kc * 32, &Bs[kc][sbo + p * 64 * 32]);
    }
    __syncthreads();
#pragma unroll
    for (int kc = 0; kc < 2; ++kc) {
      short8 af[2], bfr[4];
#pragma unroll
      for (int mi = 0; mi < 2; ++mi)
        af[mi] = *(const short8*)&As[kc][(wm * 32 + mi * 16 + l15) * 32 + quad * 8];
#pragma unroll
      for (int ni = 0; ni < 4; ++ni)
        bfr[ni] = *(const short8*)&Bs[kc][(wn * 64 + ni * 16 + l15) * 32 + quad * 8];
#pragma unroll
      for (int mi = 0; mi < 2; ++mi)
#pragma unroll
        for (int ni = 0; ni < 4; ++ni)
          acc[mi][ni] = __builtin_amdgcn_mfma_f32_16x16x32_bf16(af[mi], bfr[ni], acc[mi][ni], 0, 0, 0);
    }
  }

  float bv[4];
#pragma unroll
  for (int ni = 0; ni < 4; ++ni) bv[ni] = bf2f(bias[bn * 128 + wn * 64 + ni * 16 + l15]);

#pragma unroll
  for (int mi = 0; mi < 2; ++mi) {
    const int mbase = bm * 64 + wm * 32 + mi * 16 + quad * 4;
#pragma unroll
    for (int ni = 0; ni < 4; ++ni) {
      const int n = bn * 128 + wn * 64 + ni * 16 + l15;
#pragma unroll
      for (int r = 0; r < 4; ++r)
        dst[(long)(mbase + r) * 1024 + n] = acc[mi][ni][r] + bv[ni];
    }
  }
}

// ---------------- flash attention: UNCHANGED from R6/R8 (control group: 57us) ----------------
__global__ __launch_bounds__(256, 2) void attn_flash(const u16* __restrict__ Q,
                                                     const u16* __restrict__ K,
                                                     const u16* __restrict__ V,
                                                     u16* __restrict__ X) {
  __shared__ u16 KVs[4][64 * 72];  // [0..1] = K dbuf [kv][d] bf16; [2..3] = V^T dbuf [d][kv] fp16
  const int tid = threadIdx.x, w = tid >> 6, l = tid & 63;
  const int l15 = l & 15, quad = l >> 4;
  const int qh = w >> 1, kh = w & 1;  // wave = (q-half, kv-half)

  // XCD-aware swizzle: 512 blocks, 64 per XCD, 4 heads per XCD -> ~2MB K+V working set in L2
  const int bid = blockIdx.x;
  const int xcd = bid & 7, idx = bid >> 3;
  const int qx = idx & 15, bh = xcd + 8 * (idx >> 4);
  const int q0 = qx * 128;

  const u16* qp = Q + (long)bh * 2048 * 64;  // [2048][64] bf16, pre-scaled by 0.125*log2e
  const u16* kp = K + (long)bh * 2048 * 64;  // [2048][64] bf16
  const u16* vp = V + (long)bh * 2048 * 64;  // [64][2048] fp16 (V^T)

  // staging map: thread covers 16B chunks; rows r0 (0..31) and r1 (32..63)
  const int r0 = tid >> 3, c0 = tid & 7, r1 = 32 + (tid >> 3);

  // two register staging sets (A/B by tile parity) so issue(t+2) never clobbers store(t+1)
  short8 skA0, svA0, skA1, svA1, skB0, svB0, skB1, svB1;

#define ISSUE_LOADS_A(kv0) \
    skA0 = *(const short8*)(kp + (long)((kv0) + r0) * 64 + c0 * 8); \
    svA0 = *(const short8*)(vp + (long)r0 * 2048 + (kv0) + c0 * 8); \
    skA1 = *(const short8*)(kp + (long)((kv0) + r1) * 64 + c0 * 8); \
    svA1 = *(const short8*)(vp + (long)r1 * 2048 + (kv0) + c0 * 8);

#define ISSUE_LOADS_B(kv0) \
    skB0 = *(const short8*)(kp + (long)((kv0) + r0) * 64 + c0 * 8); \
    svB0 = *(const short8*)(vp + (long)r0 * 2048 + (kv0) + c0 * 8); \
    skB1 = *(const short8*)(kp + (long)((kv0) + r1) * 64 + c0 * 8); \
    svB1 = *(const short8*)(vp + (long)r1 * 2048 + (kv0) + c0 * 8);

#define STORE_TILE_A(pb_) \
    *(short8*)&KVs[pb_][r0 * 72 + c0 * 8] = skA0; \
    *(short8*)&KVs[2 + (pb_)][r0 * 72 + c0 * 8] = svA0; \
    *(short8*)&KVs[pb_][r1 * 72 + c0 * 8] = skA1; \
    *(short8*)&KVs[2 + (pb_)][r1 * 72 + c0 * 8] = svA1;

#define STORE_TILE_B(pb_) \
    *(short8*)&KVs[pb_][r0 * 72 + c0 * 8] = skB0; \
    *(short8*)&KVs[2 + (pb_)][r0 * 72 + c0 * 8] = svB0; \
    *(short8*)&KVs[pb_][r1 * 72 + c0 * 8] = skB1; \
    *(short8*)&KVs[2 + (pb_)][r1 * 72 + c0 * 8] = svB1;

  // Q fragments (B-operand of S^T = K*Q^T): lane holds Q[q = qh*64+nq*16+l15][d = kc*32+quad*8+j]
  short8 qf[4][2];
#pragma unroll
  for (int nq = 0; nq < 4; ++nq)
#pragma unroll
    for (int kc = 0; kc < 2; ++kc)
      qf[nq][kc] = *(const short8*)(qp + (long)(q0 + qh * 64 + nq * 16 + l15) * 64 + kc * 32 + quad * 8);

  // O^T partial accumulators: o[nq][nd] -> D[row = d = nd*16+quad*4+r][col = q = l15]
  floatx4 o[4][4];
#pragma unroll
  for (int nq = 0; nq < 4; ++nq)
#pragma unroll
    for (int nd = 0; nd < 4; ++nd) o[nq][nd] = (floatx4){0.f, 0.f, 0.f, 0.f};
  float den[4] = {0.f, 0.f, 0.f, 0.f};

  // butterfly lane predicates
  const bool p1 = (l & 32) != 0;
  const bool p3 = (l & 16) != 0;
  const bool p2 = p1 ^ p3;

  // 2-stage register butterfly (R1/R3 HW-verified form): pk[mk][i] (S^T pack:
  // kv_local = mk*16+quad*4+2i+{0,1}) -> pb[dw] = P^T B-frag dword
  // (kv_local = quad*8 + 2dw + {0,1}).
#define BFLY(pbv, m00, m01, m10, m11) { \
    u32 A0 = p1 ? (m10) : (m00), A1 = p1 ? (m11) : (m01); \
    u32 s0_ = p1 ? (m00) : (m10), s1_ = p1 ? (m01) : (m11); \
    u32 B0 = (u32)__shfl_xor((int)s0_, 32), B1 = (u32)__shfl_xor((int)s1_, 32); \
    u32 t0 = p2 ? A0 : B0, t1 = p2 ? A1 : B1; \
    u32 u0 = (u32)__shfl_xor((int)t0, 16), u1 = (u32)__shfl_xor((int)t1, 16); \
    u32 w0 = p2 ? B0 : A0, w1 = p2 ? B1 : A1; \
    pbv[0] = p3 ? u0 : w0; pbv[1] = p3 ? u1 : w1; \
    pbv[2] = p3 ? w0 : u0; pbv[3] = p3 ? w1 : u1; \
  }

#define ATTN_ITER(t, p, IS, ST) { \
    if ((t) < 30) { IS(((t) + 2) * 64) } \
    if ((t) < 31) { ST((p) ^ 1) } \
    const int kr0 = kh * 32 + l15, kr1 = kh * 32 + 16 + l15; \
    short8 ak00 = *(const short8*)&KVs[p][kr0 * 72 + quad * 8]; \
    short8 ak01 = *(const short8*)&KVs[p][kr0 * 72 + 32 + quad * 8]; \
    short8 ak10 = *(const short8*)&KVs[p][kr1 * 72 + quad * 8]; \
    short8 ak11 = *(const short8*)&KVs[p][kr1 * 72 + 32 + quad * 8]; \
    half8 vf0 = *(const half8*)&KVs[2 + (p)][(0 * 16 + l15) * 72 + kh * 32 + quad * 8]; \
    half8 vf1 = *(const half8*)&KVs[2 + (p)][(1 * 16 + l15) * 72 + kh * 32 + quad * 8]; \
    half8 vf2 = *(const half8*)&KVs[2 + (p)][(2 * 16 + l15) * 72 + kh * 32 + quad * 8]; \
    half8 vf3 = *(const half8*)&KVs[2 + (p)][(3 * 16 + l15) * 72 + kh * 32 + quad * 8]; \
    u32 pk[4][2][2]; \
    _Pragma("unroll") \
    for (int nq = 0; nq < 4; ++nq) { \
      floatx4 st0 = (floatx4){0.f, 0.f, 0.f, 0.f}, st1 = (floatx4){0.f, 0.f, 0.f, 0.f}; \
      st0 = __builtin_amdgcn_mfma_f32_16x16x32_bf16(ak00, qf[nq][0], st0, 0, 0, 0); \
      st0 = __builtin_amdgcn_mfma_f32_16x16x32_bf16(ak01, qf[nq][1], st0, 0, 0, 0); \
      st1 = __builtin_amdgcn_mfma_f32_16x16x32_bf16(ak10, qf[nq][0], st1, 0, 0, 0); \
      st1 = __builtin_amdgcn_mfma_f32_16x16x32_bf16(ak11, qf[nq][1], st1, 0, 0, 0); \
      float e0 = fexp2(st0[0]), e1 = fexp2(st0[1]), e2 = fexp2(st0[2]), e3 = fexp2(st0[3]); \
      den[nq] += (e0 + e1) + (e2 + e3); \
      pk[nq][0][0] = pkh(e0, e1); pk[nq][0][1] = pkh(e2, e3); \
      e0 = fexp2(st1[0]); e1 = fexp2(st1[1]); e2 = fexp2(st1[2]); e3 = fexp2(st1[3]); \
      den[nq] += (e0 + e1) + (e2 + e3); \
      pk[nq][1][0] = pkh(e0, e1); pk[nq][1][1] = pkh(e2, e3); \
    } \
    _Pragma("unroll") \
    for (int nq = 0; nq < 4; ++nq) { \
      uint4v pb; \
      BFLY(pb, pk[nq][0][0], pk[nq][0][1], pk[nq][1][0], pk[nq][1][1]) \
      half8 pbs = __builtin_bit_cast(half8, pb); \
      o[nq][0] = __builtin_amdgcn_mfma_f32_16x16x32_f16(vf0, pbs, o[nq][0], 0, 0, 0); \
      o[nq][1] = __builtin_amdgcn_mfma_f32_16x16x32_f16(vf1, pbs, o[nq][1], 0, 0, 0); \
      o[nq][2] = __builtin_amdgcn_mfma_f32_16x16x32_f16(vf2, pbs, o[nq][2], 0, 0, 0); \
      o[nq][3] = __builtin_amdgcn_mfma_f32_16x16x32_f16(vf3, pbs, o[nq][3], 0, 0, 0); \
    } \
    __syncthreads(); \
  }

  // prologue: tile 0 -> set A -> buf0; tile 1 -> set B (in flight across barrier)
  ISSUE_LOADS_A(0)
  STORE_TILE_A(0)
  ISSUE_LOADS_B(64)
  __syncthreads();

  for (int tt = 0; tt < 32; tt += 2) {
    ATTN_ITER(tt, 0, ISSUE_LOADS_A, STORE_TILE_B)
    ATTN_ITER(tt + 1, 1, ISSUE_LOADS_B, STORE_TILE_A)
  }

  // in-wave den reduction: sum quads -> per-lane full kv-half sum for q = l15
  float dsum[4];
#pragma unroll
  for (int nq = 0; nq < 4; ++nq) {
    float d = den[nq];
    d += __shfl_xor(d, 16);
    d += __shfl_xor(d, 32);
    dsum[nq] = d;
  }

  // cross-kv-half merge through the retired K/V LDS (36.9KB >= 32KB O + 0.5KB den)
  float* osc = (float*)KVs;            // [(qh*4+nq)*4+nd][lane] x floatx4  (32KB)
  float* dsc = osc + 8192;             // [(qh*4+nq)*16 + l15]              (0.5KB)
  if (kh == 1) {
#pragma unroll
    for (int nq = 0; nq < 4; ++nq)
#pragma unroll
      for (int nd = 0; nd < 4; ++nd)
        *(floatx4*)&osc[(((qh * 4 + nq) * 4 + nd) * 64 + l) * 4] = o[nq][nd];
    if (l < 16) {
#pragma unroll
      for (int nq = 0; nq < 4; ++nq) dsc[(qh * 4 + nq) * 16 + l] = dsum[nq];
    }
  }
  __syncthreads();

  if (kh == 0) {
    float rcp[4];
#pragma unroll
    for (int nq = 0; nq < 4; ++nq) rcp[nq] = 1.0f / (dsum[nq] + dsc[(qh * 4 + nq) * 16 + l15]);
    const int b = bh >> 4, h = bh & 15;
#pragma unroll
    for (int nq = 0; nq < 4; ++nq) {
      const int s = q0 + qh * 64 + nq * 16 + l15;
      u16* xrow = X + ((long)(b * 2048 + s)) * 1024 + h * 64;
#pragma unroll
      for (int nd = 0; nd < 4; ++nd) {
        floatx4 om = o[nq][nd] + *(const floatx4*)&osc[(((qh * 4 + nq) * 4 + nd) * 64 + l) * 4];
        ushortx4 u;
#pragma unroll
        for (int r = 0; r < 4; ++r) u[r] = f2bf(om[r] * rcp[nq]);
        *(ushortx4*)&xrow[nd * 16 + quad * 4] = u;
      }
    }
  }
}

extern "C" void kernel_launch(void* const* d_in, const int* in_sizes, int n_in,
                              void* d_out, int out_size, void* d_ws, size_t ws_size,
                              hipStream_t stream) {
  u16* ws = (u16*)d_ws;
  const size_t M1 = 1048576, M4 = 4194304;
  u16* NQ  = ws;                    // bf16 copies of fp32 inputs (NQ reused as Xb)
  u16* NK  = ws + M4;
  u16* NV  = ws + 2 * M4;
  u16* NWQ = ws + 3 * M4;
  u16* NWK = ws + 3 * M4 + M1;
  u16* NWV = ws + 3 * M4 + 2 * M1;
  u16* NWO = ws + 3 * M4 + 3 * M1;
  u16* NBQ = ws + 3 * M4 + 4 * M1;
  u16* NBK = NBQ + 1024;
  u16* NBV = NBQ + 2048;
  u16* NBO = NBQ + 3072;
  u16* Qb = ws + 16 * M1 + 8192;    // [32][2048][64] bf16, q*0.125*log2e
  u16* Kb = Qb + M4;                // [32][2048][64] bf16
  u16* Vb = Qb + 2 * M4;            // [32][64][2048] fp16 (V^T)
  u16* Xb = NQ;                     // [4096][1024] bf16

  CvtArg ca;
  u16* dsts[11] = {NQ, NK, NV, NWQ, NBQ, NWK, NBK, NWV, NBV, NWO, NBO};
  int sizes[11] = {(int)M4, (int)M4, (int)M4, (int)M1, 1024, (int)M1, 1024, (int)M1, 1024, (int)M1, 1024};
  int c = 0;
  for (int i = 0; i < 11; ++i) {
    ca.src[i] = (const float*)d_in[i];
    ca.dst[i] = dsts[i];
    ca.cum[i] = c;
    c += sizes[i];
  }
  ca.cum[11] = c;
  convert<<<(c / 4 + 255) / 256, 256, 0, stream>>>(ca);

  GemmArg gq{NQ, NWQ, NBQ, Qb, 0};
  GemmArg gk{NK, NWK, NBK, Kb, 1};
  GemmArg gv{NV, NWV, NBV, Vb, 2};
  gemm_nt<<<dim3(32, 8, 3), 256, 0, stream>>>(gq, gk, gv);

  attn_flash<<<dim3(512), 256, 0, stream>>>(Qb, Kb, Vb, Xb);

  gemm_o<<<dim3(512), 256, 0, stream>>>(Xb, NWO, NBO, (float*)d_out);
}